// Round 4
// baseline (195.761 us; speedup 1.0000x reference)
//
#include <hip/hip_runtime.h>

#define N_NODES 8192
#define D_IN 512
#define D_OUT 64
#define LRELU_ALPHA 0.2f
#define BK 256
#define NCHUNK (N_NODES / BK)

typedef __attribute__((ext_vector_type(8))) short bf16x8;
typedef __attribute__((ext_vector_type(4))) float f32x4;

__device__ __forceinline__ unsigned short f2bf(float x) {
    unsigned u = __float_as_uint(x);
    u += 0x7fffu + ((u >> 16) & 1u);   // round-to-nearest-even
    return (unsigned short)(u >> 16);
}

__device__ __forceinline__ float pcalc(float mk, float w2, float wh1v, float& lsum) {
    float e = wh1v + w2;
    e = fmaxf(e, LRELU_ALPHA * e);          // LeakyReLU (monotone)
    float p = (mk > 0.f) ? __expf(e) : 0.f; // no max-subtraction: |e| <= ~24, f32-safe
    lsum += p;
    return p;
}

__device__ __forceinline__ bf16x8 ldb(const unsigned short* p) {
    ushort4 lo = *(const ushort4*)p;          // k+0..3   (e=0..3)
    ushort4 hi = *(const ushort4*)(p + 16);   // k+16..19 (e=4..7)
    bf16x8 r;
    r[0] = (short)lo.x; r[1] = (short)lo.y; r[2] = (short)lo.z; r[3] = (short)lo.w;
    r[4] = (short)hi.x; r[5] = (short)hi.y; r[6] = (short)hi.z; r[7] = (short)hi.w;
    return r;
}

// ---------------- Kernel 1: Wh = h @ W; epilogue writes WhT(bf16), Wh1, Wh2 ----------------
__global__ __launch_bounds__(256) void k_gemm_wh(const float* __restrict__ h,
                                                 const float* __restrict__ W,
                                                 const float* __restrict__ a,
                                                 unsigned short* __restrict__ WhT,
                                                 float* __restrict__ Wh1,
                                                 float* __restrict__ Wh2) {
    __shared__ float hs[32][68];
    __shared__ float Ws[64][64];
    const int tid = threadIdx.x;
    const int r0 = blockIdx.x * 32;
    const int tf = tid & 15;   // feature group: f = tf*4 .. tf*4+3
    const int tr = tid >> 4;   // row group: rows tr*2, tr*2+1
    float acc[2][4] = {{0.f,0.f,0.f,0.f},{0.f,0.f,0.f,0.f}};

    for (int kc = 0; kc < D_IN; kc += 64) {
        {
            int rr = tid >> 4;
            int cc = (tid & 15) * 4;
            float4 v0 = *(const float4*)&h[(size_t)(r0 + rr) * D_IN + kc + cc];
            float4 v1 = *(const float4*)&h[(size_t)(r0 + rr + 16) * D_IN + kc + cc];
            *(float4*)&hs[rr][cc] = v0;
            *(float4*)&hs[rr + 16][cc] = v1;
        }
        #pragma unroll
        for (int p = 0; p < 4; ++p) {
            int kk = (tid >> 4) + p * 16;
            int cc = (tid & 15) * 4;
            *(float4*)&Ws[kk][cc] = *(const float4*)&W[(size_t)(kc + kk) * D_OUT + cc];
        }
        __syncthreads();
        #pragma unroll
        for (int k = 0; k < 64; k += 4) {
            float4 a0 = *(const float4*)&hs[tr*2][k];
            float4 a1 = *(const float4*)&hs[tr*2+1][k];
            float av0[4] = {a0.x, a0.y, a0.z, a0.w};
            float av1[4] = {a1.x, a1.y, a1.z, a1.w};
            #pragma unroll
            for (int kk = 0; kk < 4; ++kk) {
                float4 b = *(const float4*)&Ws[k+kk][tf*4];
                acc[0][0] += av0[kk]*b.x; acc[0][1] += av0[kk]*b.y;
                acc[0][2] += av0[kk]*b.z; acc[0][3] += av0[kk]*b.w;
                acc[1][0] += av1[kk]*b.x; acc[1][1] += av1[kk]*b.y;
                acc[1][2] += av1[kk]*b.z; acc[1][3] += av1[kk]*b.w;
            }
        }
        __syncthreads();
    }
    const int orow = r0 + tr*2;

    // WhT[f][row] bf16, row-pair packed as one 4B store (orow is even)
    #pragma unroll
    for (int k = 0; k < 4; ++k) {
        unsigned v = (unsigned)f2bf(acc[0][k]) | ((unsigned)f2bf(acc[1][k]) << 16);
        *(unsigned*)&WhT[(size_t)(tf*4 + k) * N_NODES + orow] = v;
    }

    // Wh1[row] = Wh[row]·a[:64], Wh2[row] = Wh[row]·a[64:]
    float a1v[4], a2v[4];
    #pragma unroll
    for (int k = 0; k < 4; ++k) { a1v[k] = a[tf*4 + k]; a2v[k] = a[64 + tf*4 + k]; }
    float s1 = 0.f, t1 = 0.f, s2 = 0.f, t2 = 0.f;
    #pragma unroll
    for (int k = 0; k < 4; ++k) {
        s1 += acc[0][k] * a1v[k];
        t1 += acc[1][k] * a1v[k];
        s2 += acc[0][k] * a2v[k];
        t2 += acc[1][k] * a2v[k];
    }
    #pragma unroll
    for (int d = 1; d < 16; d <<= 1) {
        s1 += __shfl_xor(s1, d);
        t1 += __shfl_xor(t1, d);
        s2 += __shfl_xor(s2, d);
        t2 += __shfl_xor(t2, d);
    }
    if (tf == 0) {
        Wh1[orow] = s1; Wh1[orow + 1] = t1;
        Wh2[orow] = s2; Wh2[orow + 1] = t2;
    }
}

// ---------------- Kernel 2: dense fused masked-softmax + PV via MFMA ----------------
// Block = 16 output rows; 4 waves split K (wave w owns k-steps 2w,2w+1 of each BK=256
// chunk). p is computed per-lane DIRECTLY in mfma_f32_16x16x32_bf16 A-fragment layout
// (lane l: row = l&15, k = 16*(e>>2) + (l>>4)*4 + (e&3)), so the mask load IS the
// fragment load and each element is touched exactly once. B comes from WhT bf16
// [64][8192] (k-contiguous 8B loads, L2-resident). lsum per-lane lives in one row.
// No softmax max-subtraction (|e|<=~24, f32-safe). Manual 2-chunk register dbuf.
__global__ __launch_bounds__(256) void k_attn(const float* __restrict__ mask,
                                              const unsigned short* __restrict__ WhT,
                                              const float* __restrict__ Wh1,
                                              const float* __restrict__ Wh2,
                                              float* __restrict__ out) {
    __shared__ float accbuf[4][16][68];
    __shared__ float lsumbuf[4][16];

    const int wave = threadIdx.x >> 6;
    const int lane = threadIdx.x & 63;
    const int i16 = lane & 15;     // A row within tile / B col within tile
    const int g   = lane >> 4;     // k sub-group
    const int R   = blockIdx.x * 16;

    const float wh1v = Wh1[R + i16];
    const float* mrow = mask + (size_t)(R + i16) * N_NODES;
    const int kwoff = wave * 64 + g * 4;   // this wave's k offset within a chunk

    f32x4 acc0 = {0.f,0.f,0.f,0.f}, acc1 = {0.f,0.f,0.f,0.f};
    f32x4 acc2 = {0.f,0.f,0.f,0.f}, acc3 = {0.f,0.f,0.f,0.f};
    float lsum = 0.f;

#define LOADMW(cidx, M0,M1,M2,M3, W0,W1,W2,W3)                      \
    {                                                               \
        const int co_ = (cidx) * BK + kwoff;                        \
        const float4* mp_ = (const float4*)(mrow + co_);            \
        const float4* wp_ = (const float4*)(Wh2 + co_);             \
        M0 = mp_[0]; M1 = mp_[4]; M2 = mp_[8]; M3 = mp_[12];        \
        W0 = wp_[0]; W1 = wp_[4]; W2 = wp_[8]; W3 = wp_[12];        \
    }

#define COMPUTE(cidx, M0,M1,M2,M3, W0,W1,W2,W3)                                   \
    {                                                                             \
        bf16x8 af0, af1;                                                          \
        af0[0]=(short)f2bf(pcalc(M0.x,W0.x,wh1v,lsum));                           \
        af0[1]=(short)f2bf(pcalc(M0.y,W0.y,wh1v,lsum));                           \
        af0[2]=(short)f2bf(pcalc(M0.z,W0.z,wh1v,lsum));                           \
        af0[3]=(short)f2bf(pcalc(M0.w,W0.w,wh1v,lsum));                           \
        af0[4]=(short)f2bf(pcalc(M1.x,W1.x,wh1v,lsum));                           \
        af0[5]=(short)f2bf(pcalc(M1.y,W1.y,wh1v,lsum));                           \
        af0[6]=(short)f2bf(pcalc(M1.z,W1.z,wh1v,lsum));                           \
        af0[7]=(short)f2bf(pcalc(M1.w,W1.w,wh1v,lsum));                           \
        af1[0]=(short)f2bf(pcalc(M2.x,W2.x,wh1v,lsum));                           \
        af1[1]=(short)f2bf(pcalc(M2.y,W2.y,wh1v,lsum));                           \
        af1[2]=(short)f2bf(pcalc(M2.z,W2.z,wh1v,lsum));                           \
        af1[3]=(short)f2bf(pcalc(M2.w,W2.w,wh1v,lsum));                           \
        af1[4]=(short)f2bf(pcalc(M3.x,W3.x,wh1v,lsum));                           \
        af1[5]=(short)f2bf(pcalc(M3.y,W3.y,wh1v,lsum));                           \
        af1[6]=(short)f2bf(pcalc(M3.z,W3.z,wh1v,lsum));                           \
        af1[7]=(short)f2bf(pcalc(M3.w,W3.w,wh1v,lsum));                           \
        const int co_ = (cidx) * BK + kwoff;                                      \
        const unsigned short* bb_ = WhT + (size_t)i16 * N_NODES + co_;            \
        bf16x8 B00 = ldb(bb_);                                                    \
        bf16x8 B10 = ldb(bb_ + 32);                                               \
        bf16x8 B01 = ldb(bb_ + 16 * N_NODES);                                     \
        bf16x8 B11 = ldb(bb_ + 16 * N_NODES + 32);                                \
        bf16x8 B02 = ldb(bb_ + 32 * N_NODES);                                     \
        bf16x8 B12 = ldb(bb_ + 32 * N_NODES + 32);                                \
        bf16x8 B03 = ldb(bb_ + 48 * N_NODES);                                     \
        bf16x8 B13 = ldb(bb_ + 48 * N_NODES + 32);                                \
        acc0 = __builtin_amdgcn_mfma_f32_16x16x32_bf16(af0, B00, acc0, 0, 0, 0);  \
        acc1 = __builtin_amdgcn_mfma_f32_16x16x32_bf16(af0, B01, acc1, 0, 0, 0);  \
        acc2 = __builtin_amdgcn_mfma_f32_16x16x32_bf16(af0, B02, acc2, 0, 0, 0);  \
        acc3 = __builtin_amdgcn_mfma_f32_16x16x32_bf16(af0, B03, acc3, 0, 0, 0);  \
        acc0 = __builtin_amdgcn_mfma_f32_16x16x32_bf16(af1, B10, acc0, 0, 0, 0);  \
        acc1 = __builtin_amdgcn_mfma_f32_16x16x32_bf16(af1, B11, acc1, 0, 0, 0);  \
        acc2 = __builtin_amdgcn_mfma_f32_16x16x32_bf16(af1, B12, acc2, 0, 0, 0);  \
        acc3 = __builtin_amdgcn_mfma_f32_16x16x32_bf16(af1, B13, acc3, 0, 0, 0);  \
    }

    float4 mA0,mA1,mA2,mA3, wA0,wA1,wA2,wA3;
    float4 mB0,mB1,mB2,mB3, wB0,wB1,wB2,wB3;
    LOADMW(0, mA0,mA1,mA2,mA3, wA0,wA1,wA2,wA3);
    for (int c = 0; c < NCHUNK; c += 2) {
        const int c1 = c + 1;                                  // NCHUNK even
        const int c2 = (c + 2 < NCHUNK) ? c + 2 : NCHUNK - 1;  // tail: redundant reload
        LOADMW(c1, mB0,mB1,mB2,mB3, wB0,wB1,wB2,wB3);
        COMPUTE(c,  mA0,mA1,mA2,mA3, wA0,wA1,wA2,wA3);
        LOADMW(c2, mA0,mA1,mA2,mA3, wA0,wA1,wA2,wA3);
        COMPUTE(c1, mB0,mB1,mB2,mB3, wB0,wB1,wB2,wB3);
    }
#undef LOADMW
#undef COMPUTE

    // lsum: combine the 4 k-subgroups holding the same row (xor 16/32 varies g only)
    lsum += __shfl_xor(lsum, 16);
    lsum += __shfl_xor(lsum, 32);
    if (lane < 16) lsumbuf[wave][lane] = lsum;

    // D layout (m89): row = g*4 + reg, col = i16
    #pragma unroll
    for (int r = 0; r < 4; ++r) {
        accbuf[wave][g*4 + r][ 0 + i16] = acc0[r];
        accbuf[wave][g*4 + r][16 + i16] = acc1[r];
        accbuf[wave][g*4 + r][32 + i16] = acc2[r];
        accbuf[wave][g*4 + r][48 + i16] = acc3[r];
    }
    __syncthreads();

    // merge 4 waves' k-partials, normalize, ELU, store
    const int tr  = threadIdx.x >> 4;        // output row 0..15
    const int tf4 = (threadIdx.x & 15) * 4;  // feature group
    float4 s0 = *(const float4*)&accbuf[0][tr][tf4];
    float4 s1 = *(const float4*)&accbuf[1][tr][tf4];
    float4 s2 = *(const float4*)&accbuf[2][tr][tf4];
    float4 s3 = *(const float4*)&accbuf[3][tr][tf4];
    float L = lsumbuf[0][tr] + lsumbuf[1][tr] + lsumbuf[2][tr] + lsumbuf[3][tr];
    float inv = (L > 0.f) ? 1.f / L : 0.f;
    float4 o;
    o.x = (s0.x + s1.x + s2.x + s3.x) * inv;
    o.y = (s0.y + s1.y + s2.y + s3.y) * inv;
    o.z = (s0.z + s1.z + s2.z + s3.z) * inv;
    o.w = (s0.w + s1.w + s2.w + s3.w) * inv;
    o.x = (o.x > 0.f) ? o.x : (__expf(o.x) - 1.f);
    o.y = (o.y > 0.f) ? o.y : (__expf(o.y) - 1.f);
    o.z = (o.z > 0.f) ? o.z : (__expf(o.z) - 1.f);
    o.w = (o.w > 0.f) ? o.w : (__expf(o.w) - 1.f);
    *(float4*)&out[(size_t)(R + tr) * D_OUT + tf4] = o;
}

extern "C" void kernel_launch(void* const* d_in, const int* in_sizes, int n_in,
                              void* d_out, int out_size, void* d_ws, size_t ws_size,
                              hipStream_t stream) {
    const float* h    = (const float*)d_in[0];
    const float* mask = (const float*)d_in[1];
    // d_in[2] = lamda: unused (dischange==0 makes the mask-update a no-op)
    const float* W    = (const float*)d_in[3];
    const float* a    = (const float*)d_in[4];
    float* out = (float*)d_out;

    // workspace: WhT bf16 [64][8192] (1 MB) | Wh1 f32 [8192] | Wh2 f32 [8192]
    unsigned short* WhT = (unsigned short*)d_ws;
    float* Wh1 = (float*)((char*)d_ws + (size_t)D_OUT * N_NODES * sizeof(unsigned short));
    float* Wh2 = Wh1 + N_NODES;

    k_gemm_wh<<<N_NODES / 32, 256, 0, stream>>>(h, W, a, WhT, Wh1, Wh2);
    k_attn<<<N_NODES / 16, 256, 0, stream>>>(mask, WhT, Wh1, Wh2, out);
}

// Round 5
// 184.045 us; speedup vs baseline: 1.0637x; 1.0637x over previous
//
#include <hip/hip_runtime.h>

#define N_NODES 8192
#define D_IN 512
#define D_OUT 64
#define LRELU_ALPHA 0.2f
#define BK 256
#define KSPLIT 8
#define KSLICE (N_NODES / KSPLIT)   // 1024 columns per block
#define NCHUNK_L (KSLICE / BK)      // 4 chunks per block

typedef __attribute__((ext_vector_type(8))) short bf16x8;
typedef __attribute__((ext_vector_type(4))) float f32x4;

__device__ __forceinline__ unsigned short f2bf(float x) {
    unsigned u = __float_as_uint(x);
    u += 0x7fffu + ((u >> 16) & 1u);   // round-to-nearest-even
    return (unsigned short)(u >> 16);
}

__device__ __forceinline__ float pcalc(float mk, float w2, float wh1v, float& lsum) {
    float e = wh1v + w2;
    e = fmaxf(e, LRELU_ALPHA * e);          // LeakyReLU (monotone)
    float p = (mk > 0.f) ? __expf(e) : 0.f; // no max-subtraction: |e| <= ~24, f32-safe
    lsum += p;
    return p;
}

__device__ __forceinline__ bf16x8 ldb(const unsigned short* p) {
    ushort4 lo = *(const ushort4*)p;          // k+0..3   (e=0..3)
    ushort4 hi = *(const ushort4*)(p + 16);   // k+16..19 (e=4..7)
    bf16x8 r;
    r[0] = (short)lo.x; r[1] = (short)lo.y; r[2] = (short)lo.z; r[3] = (short)lo.w;
    r[4] = (short)hi.x; r[5] = (short)hi.y; r[6] = (short)hi.z; r[7] = (short)hi.w;
    return r;
}

// ---------------- Kernel 1: Wh = h @ W; epilogue writes WhT(bf16), Wh1, Wh2 ----------------
__global__ __launch_bounds__(256) void k_gemm_wh(const float* __restrict__ h,
                                                 const float* __restrict__ W,
                                                 const float* __restrict__ a,
                                                 unsigned short* __restrict__ WhT,
                                                 float* __restrict__ Wh1,
                                                 float* __restrict__ Wh2) {
    __shared__ float hs[32][68];
    __shared__ float Ws[64][64];
    const int tid = threadIdx.x;
    const int r0 = blockIdx.x * 32;
    const int tf = tid & 15;
    const int tr = tid >> 4;
    float acc[2][4] = {{0.f,0.f,0.f,0.f},{0.f,0.f,0.f,0.f}};

    for (int kc = 0; kc < D_IN; kc += 64) {
        {
            int rr = tid >> 4;
            int cc = (tid & 15) * 4;
            float4 v0 = *(const float4*)&h[(size_t)(r0 + rr) * D_IN + kc + cc];
            float4 v1 = *(const float4*)&h[(size_t)(r0 + rr + 16) * D_IN + kc + cc];
            *(float4*)&hs[rr][cc] = v0;
            *(float4*)&hs[rr + 16][cc] = v1;
        }
        #pragma unroll
        for (int p = 0; p < 4; ++p) {
            int kk = (tid >> 4) + p * 16;
            int cc = (tid & 15) * 4;
            *(float4*)&Ws[kk][cc] = *(const float4*)&W[(size_t)(kc + kk) * D_OUT + cc];
        }
        __syncthreads();
        #pragma unroll
        for (int k = 0; k < 64; k += 4) {
            float4 a0 = *(const float4*)&hs[tr*2][k];
            float4 a1 = *(const float4*)&hs[tr*2+1][k];
            float av0[4] = {a0.x, a0.y, a0.z, a0.w};
            float av1[4] = {a1.x, a1.y, a1.z, a1.w};
            #pragma unroll
            for (int kk = 0; kk < 4; ++kk) {
                float4 b = *(const float4*)&Ws[k+kk][tf*4];
                acc[0][0] += av0[kk]*b.x; acc[0][1] += av0[kk]*b.y;
                acc[0][2] += av0[kk]*b.z; acc[0][3] += av0[kk]*b.w;
                acc[1][0] += av1[kk]*b.x; acc[1][1] += av1[kk]*b.y;
                acc[1][2] += av1[kk]*b.z; acc[1][3] += av1[kk]*b.w;
            }
        }
        __syncthreads();
    }
    const int orow = r0 + tr*2;

    #pragma unroll
    for (int k = 0; k < 4; ++k) {
        unsigned v = (unsigned)f2bf(acc[0][k]) | ((unsigned)f2bf(acc[1][k]) << 16);
        *(unsigned*)&WhT[(size_t)(tf*4 + k) * N_NODES + orow] = v;
    }

    float a1v[4], a2v[4];
    #pragma unroll
    for (int k = 0; k < 4; ++k) { a1v[k] = a[tf*4 + k]; a2v[k] = a[64 + tf*4 + k]; }
    float s1 = 0.f, t1 = 0.f, s2 = 0.f, t2 = 0.f;
    #pragma unroll
    for (int k = 0; k < 4; ++k) {
        s1 += acc[0][k] * a1v[k];
        t1 += acc[1][k] * a1v[k];
        s2 += acc[0][k] * a2v[k];
        t2 += acc[1][k] * a2v[k];
    }
    #pragma unroll
    for (int d = 1; d < 16; d <<= 1) {
        s1 += __shfl_xor(s1, d);
        t1 += __shfl_xor(t1, d);
        s2 += __shfl_xor(s2, d);
        t2 += __shfl_xor(t2, d);
    }
    if (tf == 0) {
        Wh1[orow] = s1; Wh1[orow + 1] = t1;
        Wh2[orow] = s2; Wh2[orow + 1] = t2;
    }
}

// ---------------- Kernel 2: dense masked-softmax-numerator + PV partials via MFMA ----------------
// Grid = 512 row-blocks x KSPLIT k-slices = 4096 blocks (8 blocks/CU -> full occupancy;
// R3 was grid-limited to 22%). Each block: 16 rows x 1024 cols; p computed per-lane in
// MFMA A-fragment layout; partial acc[16][64] + partial lsum[16] written to workspace
// (deterministic, no atomics). Finish kernel sums KSPLIT partials.
__global__ __launch_bounds__(256) void k_attn(const float* __restrict__ mask,
                                              const unsigned short* __restrict__ WhT,
                                              const float* __restrict__ Wh1,
                                              const float* __restrict__ Wh2,
                                              float* __restrict__ pacc,
                                              float* __restrict__ plsum) {
    __shared__ float accbuf[4][16][68];
    __shared__ float lsumbuf[4][16];

    const int wave = threadIdx.x >> 6;
    const int lane = threadIdx.x & 63;
    const int i16 = lane & 15;
    const int g   = lane >> 4;
    const int rowblk = blockIdx.x >> 3;
    const int kslice = blockIdx.x & 7;
    const int R   = rowblk * 16;

    const float wh1v = Wh1[R + i16];
    const float* mrow = mask + (size_t)(R + i16) * N_NODES + kslice * KSLICE;
    const float* w2base = Wh2 + kslice * KSLICE;
    const unsigned short* wtbase = WhT + kslice * KSLICE;
    const int kwoff = wave * 64 + g * 4;

    f32x4 acc0 = {0.f,0.f,0.f,0.f}, acc1 = {0.f,0.f,0.f,0.f};
    f32x4 acc2 = {0.f,0.f,0.f,0.f}, acc3 = {0.f,0.f,0.f,0.f};
    float lsum = 0.f;

#define LOADMW(cidx, M0,M1,M2,M3, W0,W1,W2,W3)                      \
    {                                                               \
        const int co_ = (cidx) * BK + kwoff;                        \
        const float4* mp_ = (const float4*)(mrow + co_);            \
        const float4* wp_ = (const float4*)(w2base + co_);          \
        M0 = mp_[0]; M1 = mp_[4]; M2 = mp_[8]; M3 = mp_[12];        \
        W0 = wp_[0]; W1 = wp_[4]; W2 = wp_[8]; W3 = wp_[12];        \
    }

#define COMPUTE(cidx, M0,M1,M2,M3, W0,W1,W2,W3)                                   \
    {                                                                             \
        bf16x8 af0, af1;                                                          \
        af0[0]=(short)f2bf(pcalc(M0.x,W0.x,wh1v,lsum));                           \
        af0[1]=(short)f2bf(pcalc(M0.y,W0.y,wh1v,lsum));                           \
        af0[2]=(short)f2bf(pcalc(M0.z,W0.z,wh1v,lsum));                           \
        af0[3]=(short)f2bf(pcalc(M0.w,W0.w,wh1v,lsum));                           \
        af0[4]=(short)f2bf(pcalc(M1.x,W1.x,wh1v,lsum));                           \
        af0[5]=(short)f2bf(pcalc(M1.y,W1.y,wh1v,lsum));                           \
        af0[6]=(short)f2bf(pcalc(M1.z,W1.z,wh1v,lsum));                           \
        af0[7]=(short)f2bf(pcalc(M1.w,W1.w,wh1v,lsum));                           \
        af1[0]=(short)f2bf(pcalc(M2.x,W2.x,wh1v,lsum));                           \
        af1[1]=(short)f2bf(pcalc(M2.y,W2.y,wh1v,lsum));                           \
        af1[2]=(short)f2bf(pcalc(M2.z,W2.z,wh1v,lsum));                           \
        af1[3]=(short)f2bf(pcalc(M2.w,W2.w,wh1v,lsum));                           \
        af1[4]=(short)f2bf(pcalc(M3.x,W3.x,wh1v,lsum));                           \
        af1[5]=(short)f2bf(pcalc(M3.y,W3.y,wh1v,lsum));                           \
        af1[6]=(short)f2bf(pcalc(M3.z,W3.z,wh1v,lsum));                           \
        af1[7]=(short)f2bf(pcalc(M3.w,W3.w,wh1v,lsum));                           \
        const int co_ = (cidx) * BK + kwoff;                                      \
        const unsigned short* bb_ = wtbase + (size_t)i16 * N_NODES + co_;         \
        bf16x8 B00 = ldb(bb_);                                                    \
        bf16x8 B10 = ldb(bb_ + 32);                                               \
        bf16x8 B01 = ldb(bb_ + 16 * N_NODES);                                     \
        bf16x8 B11 = ldb(bb_ + 16 * N_NODES + 32);                                \
        bf16x8 B02 = ldb(bb_ + 32 * N_NODES);                                     \
        bf16x8 B12 = ldb(bb_ + 32 * N_NODES + 32);                                \
        bf16x8 B03 = ldb(bb_ + 48 * N_NODES);                                     \
        bf16x8 B13 = ldb(bb_ + 48 * N_NODES + 32);                                \
        acc0 = __builtin_amdgcn_mfma_f32_16x16x32_bf16(af0, B00, acc0, 0, 0, 0);  \
        acc1 = __builtin_amdgcn_mfma_f32_16x16x32_bf16(af0, B01, acc1, 0, 0, 0);  \
        acc2 = __builtin_amdgcn_mfma_f32_16x16x32_bf16(af0, B02, acc2, 0, 0, 0);  \
        acc3 = __builtin_amdgcn_mfma_f32_16x16x32_bf16(af0, B03, acc3, 0, 0, 0);  \
        acc0 = __builtin_amdgcn_mfma_f32_16x16x32_bf16(af1, B10, acc0, 0, 0, 0);  \
        acc1 = __builtin_amdgcn_mfma_f32_16x16x32_bf16(af1, B11, acc1, 0, 0, 0);  \
        acc2 = __builtin_amdgcn_mfma_f32_16x16x32_bf16(af1, B12, acc2, 0, 0, 0);  \
        acc3 = __builtin_amdgcn_mfma_f32_16x16x32_bf16(af1, B13, acc3, 0, 0, 0);  \
    }

    float4 mA0,mA1,mA2,mA3, wA0,wA1,wA2,wA3;
    float4 mB0,mB1,mB2,mB3, wB0,wB1,wB2,wB3;
    LOADMW(0, mA0,mA1,mA2,mA3, wA0,wA1,wA2,wA3);
    for (int c = 0; c < NCHUNK_L; c += 2) {
        const int c1 = c + 1;
        const int c2 = (c + 2 < NCHUNK_L) ? c + 2 : NCHUNK_L - 1;  // tail: redundant reload
        LOADMW(c1, mB0,mB1,mB2,mB3, wB0,wB1,wB2,wB3);
        COMPUTE(c,  mA0,mA1,mA2,mA3, wA0,wA1,wA2,wA3);
        LOADMW(c2, mA0,mA1,mA2,mA3, wA0,wA1,wA2,wA3);
        COMPUTE(c1, mB0,mB1,mB2,mB3, wB0,wB1,wB2,wB3);
    }
#undef LOADMW
#undef COMPUTE

    lsum += __shfl_xor(lsum, 16);
    lsum += __shfl_xor(lsum, 32);
    if (lane < 16) lsumbuf[wave][lane] = lsum;

    #pragma unroll
    for (int r = 0; r < 4; ++r) {
        accbuf[wave][g*4 + r][ 0 + i16] = acc0[r];
        accbuf[wave][g*4 + r][16 + i16] = acc1[r];
        accbuf[wave][g*4 + r][32 + i16] = acc2[r];
        accbuf[wave][g*4 + r][48 + i16] = acc3[r];
    }
    __syncthreads();

    // merge 4 waves' partials, write f32 partials for this k-slice
    const int tr  = threadIdx.x >> 4;
    const int tf4 = (threadIdx.x & 15) * 4;
    float4 s0 = *(const float4*)&accbuf[0][tr][tf4];
    float4 s1 = *(const float4*)&accbuf[1][tr][tf4];
    float4 s2 = *(const float4*)&accbuf[2][tr][tf4];
    float4 s3 = *(const float4*)&accbuf[3][tr][tf4];
    float4 o;
    o.x = s0.x + s1.x + s2.x + s3.x;
    o.y = s0.y + s1.y + s2.y + s3.y;
    o.z = s0.z + s1.z + s2.z + s3.z;
    o.w = s0.w + s1.w + s2.w + s3.w;
    *(float4*)&pacc[((size_t)kslice * N_NODES + R + tr) * D_OUT + tf4] = o;
    if (threadIdx.x < 16) {
        plsum[(size_t)kslice * N_NODES + R + threadIdx.x] =
            lsumbuf[0][threadIdx.x] + lsumbuf[1][threadIdx.x] +
            lsumbuf[2][threadIdx.x] + lsumbuf[3][threadIdx.x];
    }
}

// ---------------- Kernel 3: sum KSPLIT partials, normalize, ELU ----------------
__global__ __launch_bounds__(256) void k_finish(const float* __restrict__ pacc,
                                                const float* __restrict__ plsum,
                                                float* __restrict__ out) {
    const int idx = blockIdx.x * 256 + threadIdx.x;   // one float4 per thread
    const int row = idx >> 4;
    const int tf4 = (idx & 15) * 4;
    float4 s = {0.f, 0.f, 0.f, 0.f};
    float L = 0.f;
    #pragma unroll
    for (int k = 0; k < KSPLIT; ++k) {
        float4 v = *(const float4*)&pacc[((size_t)k * N_NODES + row) * D_OUT + tf4];
        s.x += v.x; s.y += v.y; s.z += v.z; s.w += v.w;
        L += plsum[(size_t)k * N_NODES + row];
    }
    const float inv = (L > 0.f) ? 1.f / L : 0.f;
    float4 o;
    o.x = s.x * inv; o.y = s.y * inv; o.z = s.z * inv; o.w = s.w * inv;
    o.x = (o.x > 0.f) ? o.x : (__expf(o.x) - 1.f);
    o.y = (o.y > 0.f) ? o.y : (__expf(o.y) - 1.f);
    o.z = (o.z > 0.f) ? o.z : (__expf(o.z) - 1.f);
    o.w = (o.w > 0.f) ? o.w : (__expf(o.w) - 1.f);
    *(float4*)&out[(size_t)row * D_OUT + tf4] = o;
}

extern "C" void kernel_launch(void* const* d_in, const int* in_sizes, int n_in,
                              void* d_out, int out_size, void* d_ws, size_t ws_size,
                              hipStream_t stream) {
    const float* h    = (const float*)d_in[0];
    const float* mask = (const float*)d_in[1];
    // d_in[2] = lamda: unused (dischange==0 makes the mask-update a no-op)
    const float* W    = (const float*)d_in[3];
    const float* a    = (const float*)d_in[4];
    float* out = (float*)d_out;

    // ws: WhT bf16 [64][8192] (1MB) | Wh1 [8192] | Wh2 [8192] | pacc f32 [8][8192][64] (16MB) | plsum [8][8192]
    unsigned short* WhT = (unsigned short*)d_ws;
    float* Wh1 = (float*)((char*)d_ws + (size_t)D_OUT * N_NODES * sizeof(unsigned short));
    float* Wh2 = Wh1 + N_NODES;
    float* pacc = Wh2 + N_NODES;
    float* plsum = pacc + (size_t)KSPLIT * N_NODES * D_OUT;

    k_gemm_wh<<<N_NODES / 32, 256, 0, stream>>>(h, W, a, WhT, Wh1, Wh2);
    k_attn<<<(N_NODES / 16) * KSPLIT, 256, 0, stream>>>(mask, WhT, Wh1, Wh2, pacc, plsum);
    k_finish<<<(N_NODES * D_OUT / 4) / 256, 256, 0, stream>>>(pacc, plsum, out);
}